// Round 1
// 310.007 us; speedup vs baseline: 1.0233x; 1.0233x over previous
//
#include <hip/hip_runtime.h>

typedef _Float16 f16x8 __attribute__((ext_vector_type(8)));
typedef float    f32x4 __attribute__((ext_vector_type(4)));

#define NSTEP 512
#define CHUNK 8
#define NCHUNK (NSTEP / CHUNK)
#define LOG2E     1.4426950408889634f
#define TWOLOG2E  2.8853900817779268f

__device__ __forceinline__ float exp2_(float v) { return __builtin_amdgcn_exp2f(v); }

// Exp2-domain 7-trans LSTM activation. Gates arrive PRE-SCALED from the MFMA:
// gi,gf,go = -log2(e)*(preact), gg = +2log2(e)*(preact).
__device__ __forceinline__ float lstm_act_(float gi, float gf, float gg, float go, float& c) {
    float eg = exp2_(gg);
    float ei = exp2_(gi);
    float ef = exp2_(gf);
    float eo = exp2_(go);
    float X  = (eg + 1.0f) * (1.0f + ei);
    float Y  = 1.0f + ef;
    float r  = __builtin_amdgcn_rcpf(X * Y);
    c = fmaf(r * X, c, (eg - 1.0f) * (r * Y));
    float ec = exp2_(fminf(c * TWOLOG2E, 30.0f));
    float r2 = __builtin_amdgcn_rcpf((ec + 1.0f) * (1.0f + eo));
    return (ec - 1.0f) * r2;
}
__device__ __forceinline__ float sig_(float v) {
    return __builtin_amdgcn_rcpf(1.0f + exp2_(-v * LOG2E));
}
__device__ __forceinline__ float tanh_(float v) {
    return 1.0f - 2.0f * __builtin_amdgcn_rcpf(exp2_(v * TWOLOG2E) + 1.0f);
}

// R16: chunked ax-precompute. Every 8 steps: (A) build 8-step emb panel in LDS
// (prefetched x), (B) 8 independent MFMAs -> ax[j] = Wih*e(t)+b in REGISTERS
// (C-layout lands ax in the exact lane that consumes it), (C) 8 recurrence
// steps, each only: 2 ds_read_b128 (K=64 h-panel) -> 2 chained MFMA (seeded
// ax[j]) -> activation -> 1 ds_write_b16 -> barrier. Full unroll of C makes
// buffer parity (j&1) compile-time: all LDS addrs are base + immediate.
__global__ __launch_bounds__(1024, 1) void lstm_mfma16_kernel(
    const float* __restrict__ x,     const float* __restrict__ Wemb,
    const float* __restrict__ Wih1,  const float* __restrict__ Whh1,
    const float* __restrict__ b1,    const float* __restrict__ Wih2,
    const float* __restrict__ b2,    const float* __restrict__ Wout,
    const float* __restrict__ bout,  float* __restrict__ out)
{
    __shared__ __align__(16) _Float16 P[2][2][4][16][8];    // 4096 B  h-panel (K=64), dbuf
    __shared__ __align__(16) _Float16 Pe[CHUNK][4][16][8];  // 8192 B  emb panel (K=32 x 8 steps)
    __shared__ __align__(16) float h2tmp[16 * 64];          // 4096 B
    __shared__ __align__(16) float h2s[256 * 16];           // 16384 B
    __shared__ float part[64 * 16 * 2];                     // 8192 B

    const int t   = threadIdx.x;
    const int l   = t & 63;
    const int tau = t >> 6;      // wave = tile 0..15
    const int m   = l & 15;      // A-row / B col (batch) / D col
    const int q   = l >> 4;      // quad
    const int b0  = blockIdx.x * 16;

    // ---- weight fragments (exp2-domain scaled) -----------------------------
    f16x8 whh[2], whE;
    {
        const int g = m & 3;                               // gate of this A-row
        const float sc = (g == 2) ? TWOLOG2E : -LOG2E;     // i,f,o:-log2e  g:+2log2e
        const int n = g * 64 + 4 * tau + (m >> 2);         // gate-matrix row
        #pragma unroll
        for (int c = 0; c < 2; ++c) {
            #pragma unroll
            for (int jj = 0; jj < 8; ++jj)
                whh[c][jj] = (_Float16)(Whh1[n * 64 + c * 32 + (q << 3) + jj] * sc);
        }
        #pragma unroll
        for (int jj = 0; jj < 8; ++jj) {
            int k = (q << 3) + jj;
            whE[jj] = (_Float16)((k < 20) ? Wih1[n * 20 + k] * sc : 0.0f);
        }
    }
    f32x4 bias4;
    #pragma unroll
    for (int r = 0; r < 4; ++r) {
        float sc = (r == 2) ? TWOLOG2E : -LOG2E;
        bias4[r] = b1[r * 64 + 4 * tau + q] * sc;
    }

    // lane's act cell: (unit myu, batch m); h write address (parity-0 buffer)
    const int myu = 4 * tau + q;
    _Float16* hw0 = &P[0][myu >> 5][(myu >> 3) & 3][m][myu & 7];
    // parity stride = one P buffer = 2*4*16*8 = 1024 f16

    // ---- emb writer slots: v = t + 1024k, k=0..2, valid iff v < 8*320 ------
    // pair = v/20 -> (batch = pair&15, s = pair>>4), dim d = v%20
    const float* xp[3]; _Float16* pe[3];
    float we0[3], we1[3];
    bool val[3];
    float2 xv[3];
    #pragma unroll
    for (int k = 0; k < 3; ++k) {
        int v  = t + 1024 * k;
        val[k] = (v < CHUNK * 320);
        int vv = val[k] ? v : 0;
        int d  = vv % 20, pr = vv / 20;
        int bb = pr & 15, s = pr >> 4;
        we0[k] = Wemb[2 * d];
        we1[k] = Wemb[2 * d + 1];
        pe[k]  = &Pe[s][d >> 3][bb][d & 7];
        xp[k]  = x + (size_t)(b0 + bb) * (2 * NSTEP) + 2 * s;
        xv[k]  = *(const float2*)xp[k];                    // chunk-0 prefetch
    }

    // ---- zero P[0] (h(-1)=0) and Pe (pad dims 20..31 stay 0 forever) -------
    ((_Float16*)P)[t] = (_Float16)0.0f;                    // first 1024 f16 = P[0]
    {
        _Float16* pz = (_Float16*)Pe;
        #pragma unroll
        for (int k = 0; k < 4; ++k) pz[t + 1024 * k] = (_Float16)0.0f;
    }
    __syncthreads();

    // ---- main recurrence: 64 chunks x 8 steps ------------------------------
    float cst = 0.0f;
    for (int ch = 0; ch < NCHUNK; ++ch) {
        // phase A: emb panel for steps ch*8 .. ch*8+7; issue next chunk's x loads
        #pragma unroll
        for (int k = 0; k < 3; ++k)
            if (val[k])
                *pe[k] = (_Float16)fmaxf(fmaf(xv[k].x, we0[k], xv[k].y * we1[k]), 0.0f);
        if (ch + 1 < NCHUNK) {
            #pragma unroll
            for (int k = 0; k < 3; ++k) { xp[k] += 16; xv[k] = *(const float2*)xp[k]; }
        }
        __syncthreads();

        // phase B: ax[j] = Wih*e(t) + b, kept in registers (lane == consumer)
        f32x4 ax[CHUNK];
        #pragma unroll
        for (int j = 0; j < CHUNK; ++j) {
            f16x8 fe = *(const f16x8*)&Pe[j][q][m][0];
            ax[j] = __builtin_amdgcn_mfma_f32_16x16x32_f16(whE, fe, bias4, 0, 0, 0);
        }

        // phase C: 8 recurrence steps, parity static per unrolled slot
        #pragma unroll
        for (int j = 0; j < CHUNK; ++j) {
            const int pr = j & 1;
            f16x8 f0 = *(const f16x8*)&P[pr][0][q][m][0];
            f16x8 f1 = *(const f16x8*)&P[pr][1][q][m][0];
            f32x4 a = __builtin_amdgcn_mfma_f32_16x16x32_f16(whh[0], f0, ax[j], 0, 0, 0);
            a = __builtin_amdgcn_mfma_f32_16x16x32_f16(whh[1], f1, a, 0, 0, 0);
            float hv = lstm_act_(a[0], a[1], a[2], a[3], cst);
            hw0[(pr ^ 1) * 1024] = (_Float16)hv;
            __syncthreads();
        }
    }
    // final h(511) in P[0]

    // ---- epilogue: h64 to fp32 (1024 values, one per thread) ---------------
    {
        int b = t >> 6, k = t & 63;
        h2tmp[t] = (float)P[0][k >> 5][(k >> 3) & 3][b][k & 7];
    }
    __syncthreads();

    // ---- LSTM2 (single step, h=c=0 -> f-gate irrelevant) -------------------
    {
        const int u = t & 255;
        const int bh0 = (t >> 8) * 4;
        float acci[4], accg[4], acco[4];
        float bi2 = b2[u], bg2 = b2[512 + u], bo2 = b2[768 + u];
        #pragma unroll
        for (int b = 0; b < 4; ++b) { acci[b] = bi2; accg[b] = bg2; acco[b] = bo2; }
        for (int k4 = 0; k4 < 64; k4 += 4) {
            float4 wi = *(const float4*)&Wih2[(size_t)u * 64 + k4];
            float4 wg = *(const float4*)&Wih2[(size_t)(512 + u) * 64 + k4];
            float4 wo = *(const float4*)&Wih2[(size_t)(768 + u) * 64 + k4];
            #pragma unroll
            for (int b = 0; b < 4; ++b) {
                float4 hb = *(const float4*)&h2tmp[(bh0 + b) * 64 + k4];
                acci[b] += wi.x * hb.x + wi.y * hb.y + wi.z * hb.z + wi.w * hb.w;
                accg[b] += wg.x * hb.x + wg.y * hb.y + wg.z * hb.z + wg.w * hb.w;
                acco[b] += wo.x * hb.x + wo.y * hb.y + wo.z * hb.z + wo.w * hb.w;
            }
        }
        #pragma unroll
        for (int b = 0; b < 4; ++b) {
            float c2 = sig_(acci[b]) * tanh_(accg[b]);
            h2s[u * 16 + bh0 + b] = sig_(acco[b]) * tanh_(c2);
        }
    }
    __syncthreads();

    // ---- output projection --------------------------------------------------
    {
        int b = t & 15, grp = t >> 4;            // 64 groups x 4 units
        float p0 = 0.f, p1 = 0.f;
        #pragma unroll
        for (int uu = grp * 4; uu < grp * 4 + 4; ++uu) {
            float hvv = h2s[uu * 16 + b];
            p0 += hvv * Wout[uu];
            p1 += hvv * Wout[256 + uu];
        }
        part[(grp * 16 + b) * 2 + 0] = p0;
        part[(grp * 16 + b) * 2 + 1] = p1;
    }
    __syncthreads();
    if (t < 32) {
        int b = t >> 1, o = t & 1;
        float s0 = bout[o];
        for (int grp = 0; grp < 64; ++grp) s0 += part[(grp * 16 + b) * 2 + o];
        out[(size_t)(b0 + b) * 2 + o] = s0;
    }
}

extern "C" void kernel_launch(void* const* d_in, const int* in_sizes, int n_in,
                              void* d_out, int out_size, void* d_ws, size_t ws_size,
                              hipStream_t stream) {
    const float* x    = (const float*)d_in[0];
    const float* Wemb = (const float*)d_in[1];
    const float* Wih1 = (const float*)d_in[2];
    const float* Whh1 = (const float*)d_in[3];
    const float* b1   = (const float*)d_in[4];
    const float* Wih2 = (const float*)d_in[5];
    // d_in[6] = Whh2: unused (h=c=0 at LSTM2's single step)
    const float* b2   = (const float*)d_in[7];
    const float* Wout = (const float*)d_in[8];
    const float* bout = (const float*)d_in[9];
    float* out = (float*)d_out;

    lstm_mfma16_kernel<<<256, 1024, 0, stream>>>(
        x, Wemb, Wih1, Whh1, b1, Wih2, b2, Wout, bout, out);
}

// Round 2
// 297.141 us; speedup vs baseline: 1.0676x; 1.0433x over previous
//
#include <hip/hip_runtime.h>

typedef _Float16 f16x8 __attribute__((ext_vector_type(8)));
typedef float    f32x4 __attribute__((ext_vector_type(4)));

#define NSTEP 512
#define CHUNK 8
#define NCHUNK (NSTEP / CHUNK)
#define LOG2E     1.4426950408889634f
#define TWOLOG2E  2.8853900817779268f

__device__ __forceinline__ float exp2_(float v) { return __builtin_amdgcn_exp2f(v); }

// Exp2-domain 7-trans LSTM activation. Gates arrive PRE-SCALED from the MFMA:
// gi,gf,go = -log2(e)*(preact), gg = +2log2(e)*(preact).
__device__ __forceinline__ float lstm_act_(float gi, float gf, float gg, float go, float& c) {
    float eg = exp2_(gg);
    float ei = exp2_(gi);
    float ef = exp2_(gf);
    float eo = exp2_(go);
    float X  = (eg + 1.0f) * (1.0f + ei);
    float Y  = 1.0f + ef;
    float r  = __builtin_amdgcn_rcpf(X * Y);
    c = fmaf(r * X, c, (eg - 1.0f) * (r * Y));
    float ec = exp2_(fminf(c * TWOLOG2E, 30.0f));
    float r2 = __builtin_amdgcn_rcpf((ec + 1.0f) * (1.0f + eo));
    return (ec - 1.0f) * r2;
}
__device__ __forceinline__ float sig_(float v) {
    return __builtin_amdgcn_rcpf(1.0f + exp2_(-v * LOG2E));
}
__device__ __forceinline__ float tanh_(float v) {
    return 1.0f - 2.0f * __builtin_amdgcn_rcpf(exp2_(v * TWOLOG2E) + 1.0f);
}

// R17: 8 waves x 2 tiles (512 thr). The two tiles of a wave share the SAME
// h-panel B fragments -> LDS reads/step halve (32->16 b128 per CU), barrier
// syncs 8 waves not 16, issue work per CU conserved (2 acts/wave). Chunked
// ax-precompute retained: per 8 steps, emb panel -> 16 reg-resident ax MFMAs.
// Per recurrence step/wave: 2 ds_read_b128 -> 2x2 independent MFMA pairs ->
// 2 activations -> 2 ds_write_b16 -> barrier.
__global__ __launch_bounds__(512, 2) void lstm_mfma16_kernel(
    const float* __restrict__ x,     const float* __restrict__ Wemb,
    const float* __restrict__ Wih1,  const float* __restrict__ Whh1,
    const float* __restrict__ b1,    const float* __restrict__ Wih2,
    const float* __restrict__ b2,    const float* __restrict__ Wout,
    const float* __restrict__ bout,  float* __restrict__ out)
{
    __shared__ __align__(16) _Float16 P[2][2][4][16][8];    // 4096 B  h-panel (K=64), dbuf
    __shared__ __align__(16) _Float16 Pe[CHUNK][4][16][8];  // 8192 B  emb panel (K=32 x 8 steps)
    __shared__ __align__(16) float h2tmp[16 * 64];          // 4096 B
    __shared__ __align__(16) float h2s[256 * 16];           // 16384 B
    __shared__ float part[32 * 16 * 2];                     // 4096 B

    const int t   = threadIdx.x;
    const int l   = t & 63;
    const int w   = t >> 6;      // wave 0..7; owns tiles 2w, 2w+1
    const int m   = l & 15;      // A-row / B col (batch) / D col
    const int q   = l >> 4;      // quad
    const int b0  = blockIdx.x * 16;

    // ---- weight fragments for both tiles (exp2-domain scaled) --------------
    f16x8 whh[2][2], whE[2];
    f32x4 bias4[2];
    #pragma unroll
    for (int tt = 0; tt < 2; ++tt) {
        const int tau = 2 * w + tt;
        const int g = m & 3;
        const float sc = (g == 2) ? TWOLOG2E : -LOG2E;
        const int n = g * 64 + 4 * tau + (m >> 2);
        #pragma unroll
        for (int c = 0; c < 2; ++c)
            #pragma unroll
            for (int jj = 0; jj < 8; ++jj)
                whh[tt][c][jj] = (_Float16)(Whh1[n * 64 + c * 32 + (q << 3) + jj] * sc);
        #pragma unroll
        for (int jj = 0; jj < 8; ++jj) {
            int k = (q << 3) + jj;
            whE[tt][jj] = (_Float16)((k < 20) ? Wih1[n * 20 + k] * sc : 0.0f);
        }
        #pragma unroll
        for (int r = 0; r < 4; ++r) {
            float scr = (r == 2) ? TWOLOG2E : -LOG2E;
            bias4[tt][r] = b1[r * 64 + 4 * tau + q] * scr;
        }
    }

    // lane's act cells: units 8w+q (tile A), 8w+4+q (tile B), batch m
    const int myuA = 8 * w + q;
    const int myuB = 8 * w + 4 + q;
    _Float16* hwA = &P[0][myuA >> 5][(myuA >> 3) & 3][m][myuA & 7];
    _Float16* hwB = &P[0][myuB >> 5][(myuB >> 3) & 3][m][myuB & 7];
    const _Float16* rb = &P[0][0][q][m][0];   // B-fragment base (lane-linear)
    // parity stride = one P buffer = 1024 f16

    // ---- emb writer slots: v = t + 512k, k=0..4 (2560 = 5*512, all valid) --
    // pair = v/20 -> (batch = pair&15, s = pair>>4), dim d = v%20
    const float* xp[5]; _Float16* pe[5];
    float we0[5], we1[5];
    float2 xv[5];
    #pragma unroll
    for (int k = 0; k < 5; ++k) {
        int v  = t + 512 * k;
        int d  = v % 20, pr = v / 20;
        int bb = pr & 15, s = pr >> 4;
        we0[k] = Wemb[2 * d];
        we1[k] = Wemb[2 * d + 1];
        pe[k]  = &Pe[s][d >> 3][bb][d & 7];
        xp[k]  = x + (size_t)(b0 + bb) * (2 * NSTEP) + 2 * s;
        xv[k]  = *(const float2*)xp[k];                    // chunk-0 prefetch
    }

    // ---- zero P[0] (h(-1)=0) and Pe (pad dims 20..31 stay 0 forever) -------
    ((_Float16*)P)[t]       = (_Float16)0.0f;
    ((_Float16*)P)[t + 512] = (_Float16)0.0f;
    {
        _Float16* pz = (_Float16*)Pe;
        #pragma unroll
        for (int k = 0; k < 8; ++k) pz[t + 512 * k] = (_Float16)0.0f;
    }
    __syncthreads();

    // ---- main recurrence: 64 chunks x 8 steps ------------------------------
    float cA = 0.0f, cB = 0.0f;
    for (int ch = 0; ch < NCHUNK; ++ch) {
        // phase A: emb panel for steps ch*8..ch*8+7; prefetch next chunk's x
        #pragma unroll
        for (int k = 0; k < 5; ++k)
            *pe[k] = (_Float16)fmaxf(fmaf(xv[k].x, we0[k], xv[k].y * we1[k]), 0.0f);
        if (ch + 1 < NCHUNK) {
            #pragma unroll
            for (int k = 0; k < 5; ++k) { xp[k] += 16; xv[k] = *(const float2*)xp[k]; }
        }
        __syncthreads();

        // phase B: ax[tile][j] = Wih*e(t) + b, in registers (lane == consumer)
        f32x4 axA[CHUNK], axB[CHUNK];
        #pragma unroll
        for (int j = 0; j < CHUNK; ++j) {
            f16x8 fe = *(const f16x8*)&Pe[j][q][m][0];
            axA[j] = __builtin_amdgcn_mfma_f32_16x16x32_f16(whE[0], fe, bias4[0], 0, 0, 0);
            axB[j] = __builtin_amdgcn_mfma_f32_16x16x32_f16(whE[1], fe, bias4[1], 0, 0, 0);
        }

        // phase C: 8 recurrence steps, parity static per unrolled slot
        #pragma unroll
        for (int j = 0; j < CHUNK; ++j) {
            const int pr = j & 1;
            f16x8 f0 = *(const f16x8*)(rb + pr * 1024);
            f16x8 f1 = *(const f16x8*)(rb + pr * 1024 + 512);
            f32x4 aA = __builtin_amdgcn_mfma_f32_16x16x32_f16(whh[0][0], f0, axA[j], 0, 0, 0);
            f32x4 aB = __builtin_amdgcn_mfma_f32_16x16x32_f16(whh[1][0], f0, axB[j], 0, 0, 0);
            aA = __builtin_amdgcn_mfma_f32_16x16x32_f16(whh[0][1], f1, aA, 0, 0, 0);
            aB = __builtin_amdgcn_mfma_f32_16x16x32_f16(whh[1][1], f1, aB, 0, 0, 0);
            float hA = lstm_act_(aA[0], aA[1], aA[2], aA[3], cA);
            float hB = lstm_act_(aB[0], aB[1], aB[2], aB[3], cB);
            hwA[(pr ^ 1) * 1024] = (_Float16)hA;
            hwB[(pr ^ 1) * 1024] = (_Float16)hB;
            __syncthreads();
        }
    }
    // final h(511) in P[0]

    // ---- epilogue: h64 to fp32 (1024 values, two per thread) ---------------
    #pragma unroll
    for (int r = 0; r < 2; ++r) {
        int tt = t + 512 * r;
        int b = tt >> 6, k = tt & 63;
        h2tmp[tt] = (float)P[0][k >> 5][(k >> 3) & 3][b][k & 7];
    }
    __syncthreads();

    // ---- LSTM2 (single step, h=c=0 -> f-gate irrelevant) -------------------
    {
        const int u = t & 255;
        const int bh0 = (t >> 8) * 8;               // 2 groups x 8 batches
        float acci[8], accg[8], acco[8];
        float bi2 = b2[u], bg2 = b2[512 + u], bo2 = b2[768 + u];
        #pragma unroll
        for (int b = 0; b < 8; ++b) { acci[b] = bi2; accg[b] = bg2; acco[b] = bo2; }
        for (int k4 = 0; k4 < 64; k4 += 4) {
            float4 wi = *(const float4*)&Wih2[(size_t)u * 64 + k4];
            float4 wg = *(const float4*)&Wih2[(size_t)(512 + u) * 64 + k4];
            float4 wo = *(const float4*)&Wih2[(size_t)(768 + u) * 64 + k4];
            #pragma unroll
            for (int b = 0; b < 8; ++b) {
                float4 hb = *(const float4*)&h2tmp[(bh0 + b) * 64 + k4];
                acci[b] += wi.x * hb.x + wi.y * hb.y + wi.z * hb.z + wi.w * hb.w;
                accg[b] += wg.x * hb.x + wg.y * hb.y + wg.z * hb.z + wg.w * hb.w;
                acco[b] += wo.x * hb.x + wo.y * hb.y + wo.z * hb.z + wo.w * hb.w;
            }
        }
        #pragma unroll
        for (int b = 0; b < 8; ++b) {
            float c2 = sig_(acci[b]) * tanh_(accg[b]);
            h2s[u * 16 + bh0 + b] = sig_(acco[b]) * tanh_(c2);
        }
    }
    __syncthreads();

    // ---- output projection --------------------------------------------------
    {
        int b = t & 15, grp = t >> 4;            // 32 groups x 8 units
        float p0 = 0.f, p1 = 0.f;
        #pragma unroll
        for (int uu = grp * 8; uu < grp * 8 + 8; ++uu) {
            float hvv = h2s[uu * 16 + b];
            p0 += hvv * Wout[uu];
            p1 += hvv * Wout[256 + uu];
        }
        part[(grp * 16 + b) * 2 + 0] = p0;
        part[(grp * 16 + b) * 2 + 1] = p1;
    }
    __syncthreads();
    if (t < 32) {
        int b = t >> 1, o = t & 1;
        float s0 = bout[o];
        for (int grp = 0; grp < 32; ++grp) s0 += part[(grp * 16 + b) * 2 + o];
        out[(size_t)(b0 + b) * 2 + o] = s0;
    }
}

extern "C" void kernel_launch(void* const* d_in, const int* in_sizes, int n_in,
                              void* d_out, int out_size, void* d_ws, size_t ws_size,
                              hipStream_t stream) {
    const float* x    = (const float*)d_in[0];
    const float* Wemb = (const float*)d_in[1];
    const float* Wih1 = (const float*)d_in[2];
    const float* Whh1 = (const float*)d_in[3];
    const float* b1   = (const float*)d_in[4];
    const float* Wih2 = (const float*)d_in[5];
    // d_in[6] = Whh2: unused (h=c=0 at LSTM2's single step)
    const float* b2   = (const float*)d_in[7];
    const float* Wout = (const float*)d_in[8];
    const float* bout = (const float*)d_in[9];
    float* out = (float*)d_out;

    lstm_mfma16_kernel<<<256, 512, 0, stream>>>(
        x, Wemb, Wih1, Whh1, b1, Wih2, b2, Wout, bout, out);
}

// Round 3
// 291.675 us; speedup vs baseline: 1.0876x; 1.0187x over previous
//
#include <hip/hip_runtime.h>

typedef _Float16 f16x8 __attribute__((ext_vector_type(8)));
typedef float    f32x4 __attribute__((ext_vector_type(4)));

#define NSTEP 512
#define CHUNK 8
#define NCHUNK (NSTEP / CHUNK)
#define LOG2E     1.4426950408889634f
#define TWOLOG2E  2.8853900817779268f

__device__ __forceinline__ float exp2_(float v) { return __builtin_amdgcn_exp2f(v); }

// Exp2-domain 7-trans LSTM activation. Gates arrive PRE-SCALED from the MFMA:
// gi,gf,go = -log2(e)*(preact), gg = +2log2(e)*(preact).
__device__ __forceinline__ float lstm_act_(float gi, float gf, float gg, float go, float& c) {
    float eg = exp2_(gg);
    float ei = exp2_(gi);
    float ef = exp2_(gf);
    float eo = exp2_(go);
    float X  = (eg + 1.0f) * (1.0f + ei);
    float Y  = 1.0f + ef;
    float r  = __builtin_amdgcn_rcpf(X * Y);
    c = fmaf(r * X, c, (eg - 1.0f) * (r * Y));
    float ec = exp2_(fminf(c * TWOLOG2E, 30.0f));
    float r2 = __builtin_amdgcn_rcpf((ec + 1.0f) * (1.0f + eo));
    return (ec - 1.0f) * r2;
}
__device__ __forceinline__ float sig_(float v) {
    return __builtin_amdgcn_rcpf(1.0f + exp2_(-v * LOG2E));
}
__device__ __forceinline__ float tanh_(float v) {
    return 1.0f - 2.0f * __builtin_amdgcn_rcpf(exp2_(v * TWOLOG2E) + 1.0f);
}

// lgkmcnt-only barrier: does NOT drain vmcnt, so global x-prefetch loads float
// across the whole chunk. asm "memory" fences pin LDS ops on both sides.
__device__ __forceinline__ void bar_() {
    asm volatile("s_waitcnt lgkmcnt(0)" ::: "memory");
    __builtin_amdgcn_s_barrier();
    asm volatile("" ::: "memory");
}

// R18: phase-A eliminated. Pe double-buffered; step 0 of each chunk writes the
// NEXT chunk's emb panel (xv regs) and re-issues the x prefetch, whose vmcnt is
// never drained by a barrier (raw lgkmcnt-only barriers in the main loop).
// Per recurrence step/wave: 2 ds_read_b128 -> 2x2 chained MFMA (seeded with
// reg-resident ax[j]) -> 2 activations -> 2 ds_write_b16 -> barrier.
__global__ __launch_bounds__(512, 2) void lstm_mfma16_kernel(
    const float* __restrict__ x,     const float* __restrict__ Wemb,
    const float* __restrict__ Wih1,  const float* __restrict__ Whh1,
    const float* __restrict__ b1,    const float* __restrict__ Wih2,
    const float* __restrict__ b2,    const float* __restrict__ Wout,
    const float* __restrict__ bout,  float* __restrict__ out)
{
    __shared__ __align__(16) _Float16 P[2][2][4][16][8];       // 4096 B  h-panel dbuf
    __shared__ __align__(16) _Float16 Pe[2][CHUNK][4][16][8];  // 16384 B emb panel dbuf
    __shared__ __align__(16) float h2tmp[16 * 64];             // 4096 B
    __shared__ __align__(16) float h2s[256 * 16];              // 16384 B
    __shared__ float part[32 * 16 * 2];                        // 4096 B

    const int t   = threadIdx.x;
    const int l   = t & 63;
    const int w   = t >> 6;      // wave 0..7; owns tiles 2w, 2w+1
    const int m   = l & 15;      // A-row / B col (batch) / D col
    const int q   = l >> 4;      // quad
    const int b0  = blockIdx.x * 16;

    // ---- weight fragments for both tiles (exp2-domain scaled) --------------
    f16x8 whh[2][2], whE[2];
    f32x4 bias4[2];
    #pragma unroll
    for (int tt = 0; tt < 2; ++tt) {
        const int tau = 2 * w + tt;
        const int g = m & 3;
        const float sc = (g == 2) ? TWOLOG2E : -LOG2E;
        const int n = g * 64 + 4 * tau + (m >> 2);
        #pragma unroll
        for (int c = 0; c < 2; ++c)
            #pragma unroll
            for (int jj = 0; jj < 8; ++jj)
                whh[tt][c][jj] = (_Float16)(Whh1[n * 64 + c * 32 + (q << 3) + jj] * sc);
        #pragma unroll
        for (int jj = 0; jj < 8; ++jj) {
            int k = (q << 3) + jj;
            whE[tt][jj] = (_Float16)((k < 20) ? Wih1[n * 20 + k] * sc : 0.0f);
        }
        #pragma unroll
        for (int r = 0; r < 4; ++r) {
            float scr = (r == 2) ? TWOLOG2E : -LOG2E;
            bias4[tt][r] = b1[r * 64 + 4 * tau + q] * scr;
        }
    }

    // lane's act cells: units 8w+q (tile A), 8w+4+q (tile B), batch m
    const int myuA = 8 * w + q;
    const int myuB = 8 * w + 4 + q;
    _Float16* hwA = &P[0][myuA >> 5][(myuA >> 3) & 3][m][myuA & 7];
    _Float16* hwB = &P[0][myuB >> 5][(myuB >> 3) & 3][m][myuB & 7];
    const _Float16* rb = &P[0][0][q][m][0];   // B-fragment base (lane-linear)
    // parity stride = one P buffer = 1024 f16; Pe buffer stride = 4096 f16

    // ---- emb writer slots: v = t + 512k, k=0..4 (2560 = 5*512, all valid) --
    // pair = v/20 -> (batch = pair&15, s = pair>>4), dim d = v%20
    const float* xp[5]; _Float16* pe[5];
    float we0[5], we1[5];
    float2 xv[5];
    #pragma unroll
    for (int k = 0; k < 5; ++k) {
        int v  = t + 512 * k;
        int d  = v % 20, pr = v / 20;
        int bb = pr & 15, s = pr >> 4;
        we0[k] = Wemb[2 * d];
        we1[k] = Wemb[2 * d + 1];
        pe[k]  = &Pe[0][s][d >> 3][bb][d & 7];
        xp[k]  = x + (size_t)(b0 + bb) * (2 * NSTEP) + 2 * s;
        xv[k]  = *(const float2*)xp[k];                    // chunk-0 data
    }

    // ---- zero P[0] (h(-1)=0) and all of Pe (pads d=20..31 stay 0 forever) --
    ((_Float16*)P)[t]       = (_Float16)0.0f;
    ((_Float16*)P)[t + 512] = (_Float16)0.0f;
    {
        _Float16* pz = (_Float16*)Pe;
        #pragma unroll
        for (int k = 0; k < 16; ++k) pz[t + 512 * k] = (_Float16)0.0f;
    }
    __syncthreads();
    // fill Pe[0] with chunk 0's panel, then prefetch chunk 1's x
    #pragma unroll
    for (int k = 0; k < 5; ++k)
        pe[k][0] = (_Float16)fmaxf(fmaf(xv[k].x, we0[k], xv[k].y * we1[k]), 0.0f);
    #pragma unroll
    for (int k = 0; k < 5; ++k) { xp[k] += 16; xv[k] = *(const float2*)xp[k]; }
    __syncthreads();

    // ---- main recurrence: 64 chunks x 8 steps ------------------------------
    float cA = 0.0f, cB = 0.0f;
    for (int ch = 0; ch < NCHUNK; ++ch) {
        const int pb = ch & 1;                           // Pe read buffer
        const _Float16* peR = (const _Float16*)Pe + pb * 4096;

        // phase B: ax[tile][j] = Wih*e(t) + b, in registers (lane == consumer)
        f32x4 axA[CHUNK], axB[CHUNK];
        #pragma unroll
        for (int j = 0; j < CHUNK; ++j) {
            f16x8 fe = *(const f16x8*)(peR + j * 512 + q * 128 + m * 8);
            axA[j] = __builtin_amdgcn_mfma_f32_16x16x32_f16(whE[0], fe, bias4[0], 0, 0, 0);
            axB[j] = __builtin_amdgcn_mfma_f32_16x16x32_f16(whE[1], fe, bias4[1], 0, 0, 0);
        }

        // phase C: 8 recurrence steps, parity static per unrolled slot
        #pragma unroll
        for (int j = 0; j < CHUNK; ++j) {
            const int pr = j & 1;
            f16x8 f0 = *(const f16x8*)(rb + pr * 1024);
            f16x8 f1 = *(const f16x8*)(rb + pr * 1024 + 512);
            f32x4 aA = __builtin_amdgcn_mfma_f32_16x16x32_f16(whh[0][0], f0, axA[j], 0, 0, 0);
            f32x4 aB = __builtin_amdgcn_mfma_f32_16x16x32_f16(whh[1][0], f0, axB[j], 0, 0, 0);
            aA = __builtin_amdgcn_mfma_f32_16x16x32_f16(whh[0][1], f1, aA, 0, 0, 0);
            aB = __builtin_amdgcn_mfma_f32_16x16x32_f16(whh[1][1], f1, aB, 0, 0, 0);
            float hA = lstm_act_(aA[0], aA[1], aA[2], aA[3], cA);
            float hB = lstm_act_(aB[0], aB[1], aB[2], aB[3], cB);
            hwA[(pr ^ 1) * 1024] = (_Float16)hA;
            hwB[(pr ^ 1) * 1024] = (_Float16)hB;
            if (j == 0) {
                // write NEXT chunk's emb panel (buffer pb^1) from xv regs;
                // at ch==NCHUNK-1 this writes stale data to a dead buffer.
                #pragma unroll
                for (int k = 0; k < 5; ++k)
                    pe[k][(pb ^ 1) * 4096] =
                        (_Float16)fmaxf(fmaf(xv[k].x, we0[k], xv[k].y * we1[k]), 0.0f);
                if (ch + 2 < NCHUNK) {
                    #pragma unroll
                    for (int k = 0; k < 5; ++k) { xp[k] += 16; xv[k] = *(const float2*)xp[k]; }
                }
            }
            bar_();
        }
    }
    // final h(511) in P[0]

    // ---- epilogue: h64 to fp32 (1024 values, two per thread) ---------------
    #pragma unroll
    for (int r = 0; r < 2; ++r) {
        int tt = t + 512 * r;
        int b = tt >> 6, k = tt & 63;
        h2tmp[tt] = (float)P[0][k >> 5][(k >> 3) & 3][b][k & 7];
    }
    __syncthreads();

    // ---- LSTM2 (single step, h=c=0 -> f-gate irrelevant) -------------------
    {
        const int u = t & 255;
        const int bh0 = (t >> 8) * 8;               // 2 groups x 8 batches
        float acci[8], accg[8], acco[8];
        float bi2 = b2[u], bg2 = b2[512 + u], bo2 = b2[768 + u];
        #pragma unroll
        for (int b = 0; b < 8; ++b) { acci[b] = bi2; accg[b] = bg2; acco[b] = bo2; }
        for (int k4 = 0; k4 < 64; k4 += 4) {
            float4 wi = *(const float4*)&Wih2[(size_t)u * 64 + k4];
            float4 wg = *(const float4*)&Wih2[(size_t)(512 + u) * 64 + k4];
            float4 wo = *(const float4*)&Wih2[(size_t)(768 + u) * 64 + k4];
            #pragma unroll
            for (int b = 0; b < 8; ++b) {
                float4 hb = *(const float4*)&h2tmp[(bh0 + b) * 64 + k4];
                acci[b] += wi.x * hb.x + wi.y * hb.y + wi.z * hb.z + wi.w * hb.w;
                accg[b] += wg.x * hb.x + wg.y * hb.y + wg.z * hb.z + wg.w * hb.w;
                acco[b] += wo.x * hb.x + wo.y * hb.y + wo.z * hb.z + wo.w * hb.w;
            }
        }
        #pragma unroll
        for (int b = 0; b < 8; ++b) {
            float c2 = sig_(acci[b]) * tanh_(accg[b]);
            h2s[u * 16 + bh0 + b] = sig_(acco[b]) * tanh_(c2);
        }
    }
    __syncthreads();

    // ---- output projection --------------------------------------------------
    {
        int b = t & 15, grp = t >> 4;            // 32 groups x 8 units
        float p0 = 0.f, p1 = 0.f;
        #pragma unroll
        for (int uu = grp * 8; uu < grp * 8 + 8; ++uu) {
            float hvv = h2s[uu * 16 + b];
            p0 += hvv * Wout[uu];
            p1 += hvv * Wout[256 + uu];
        }
        part[(grp * 16 + b) * 2 + 0] = p0;
        part[(grp * 16 + b) * 2 + 1] = p1;
    }
    __syncthreads();
    if (t < 32) {
        int b = t >> 1, o = t & 1;
        float s0 = bout[o];
        for (int grp = 0; grp < 32; ++grp) s0 += part[(grp * 16 + b) * 2 + o];
        out[(size_t)(b0 + b) * 2 + o] = s0;
    }
}

extern "C" void kernel_launch(void* const* d_in, const int* in_sizes, int n_in,
                              void* d_out, int out_size, void* d_ws, size_t ws_size,
                              hipStream_t stream) {
    const float* x    = (const float*)d_in[0];
    const float* Wemb = (const float*)d_in[1];
    const float* Wih1 = (const float*)d_in[2];
    const float* Whh1 = (const float*)d_in[3];
    const float* b1   = (const float*)d_in[4];
    const float* Wih2 = (const float*)d_in[5];
    // d_in[6] = Whh2: unused (h=c=0 at LSTM2's single step)
    const float* b2   = (const float*)d_in[7];
    const float* Wout = (const float*)d_in[8];
    const float* bout = (const float*)d_in[9];
    float* out = (float*)d_out;

    lstm_mfma16_kernel<<<256, 512, 0, stream>>>(
        x, Wemb, Wih1, Whh1, b1, Wih2, b2, Wout, bout, out);
}